// Round 14
// baseline (220.574 us; speedup 1.0000x reference)
//
#include <hip/hip_runtime.h>
#include <hip/hip_bf16.h>
#include <math.h>

// Problem constants (match reference): N=100000, D=128, B=512, M=4, E=10, Q=5, MPT=8
constexpr int D   = 128;
constexpr int M   = 4;
constexpr int E   = 10;
constexpr int Q   = 5;
constexpr int MPT = 8;
constexpr int MXE = M * E;                       // 40
constexpr int TASKS = 1 + MXE + Q + Q * MXE;     // 246 weighted dots per b

// ---------------------------------------------------------------------------
// Kernel 1: embW = emb @ W  (fp32 vector FMA; no fp32 MFMA on CDNA4)
//
// ROUND-13 REDESIGN (no-LDS): r4/r9/r13 — three different structures all
// pinned at ~39% VALUBusy, 64-76us. Common denominator was the 64KB LDS W
// stage (occupancy cap + barrier + single LDS pipe). This version:
//  - NO LDS at all. W read directly from global; W is 64KB, L2-resident,
//    16-lane x 16B coalesced reads (~200MB aggregate vs 34.5TB/s L2).
//  - A-rows via ONE base pointer; all 16 loads/iter use compile-time
//    offsets r*512 + k*4 <= 4064B (13-bit imm) — minimal address VALU.
//  - No __syncthreads. LDS=0 -> occupancy capped by VGPR only.
//  - __launch_bounds__(256,4): 4 waves/EU target -> <=128 VGPR (live set
//    ~115: acc 64 + A 32 + W 8 + addr ~10). Spill would show as WRITE_SIZE
//    explosion (r3 signature) — that's the detectable failure mode.
//  - Tail: clamp 8-row base to nrows-8 -> duplicate groups recompute the
//    same rows with identical values (benign writes), all accesses in-range.
// ---------------------------------------------------------------------------
__global__ __launch_bounds__(256, 4)
void embw_gemm(const float* __restrict__ emb,
               const float* __restrict__ W,
               float* __restrict__ embW,
               int nrows)
{
    const int jg   = threadIdx.x & 15;   // col group: cols [4jg,4jg+4) u [64+4jg,...)
    const int rg   = threadIdx.x >> 4;   // row group 0..15: rows 8*rg .. 8*rg+7 (of 128)
    const int base = blockIdx.x * 128;
    int row0 = base + rg * 8;
    if (row0 + 8 > nrows) row0 = nrows - 8;   // benign duplicate recompute at tail

    const float* ap = emb + (size_t)row0 * D;   // A base; offsets r*512+k*4 fit imm
    const float* wp = W + jg * 4;               // advanced by 8*D per iter

    float acc[8][8];
#pragma unroll
    for (int r = 0; r < 8; ++r)
#pragma unroll
        for (int c = 0; c < 8; ++c) acc[r][c] = 0.f;

    float4 a[8];

#pragma unroll 1
    for (int i0 = 0; i0 < D; i0 += 8) {
        // ---- half 1: k = i0 .. i0+3 ----
#pragma unroll
        for (int r = 0; r < 8; ++r)
            a[r] = *reinterpret_cast<const float4*>(ap + r * D + i0);
#pragma unroll
        for (int u = 0; u < 4; ++u) {
            const float4 wlo = *reinterpret_cast<const float4*>(wp + u * D);
            const float4 whi = *reinterpret_cast<const float4*>(wp + u * D + 64);
#pragma unroll
            for (int r = 0; r < 8; ++r) {
                float e = (u == 0) ? a[r].x : (u == 1) ? a[r].y
                        : (u == 2) ? a[r].z : a[r].w;
                acc[r][0] = fmaf(e, wlo.x, acc[r][0]);
                acc[r][1] = fmaf(e, wlo.y, acc[r][1]);
                acc[r][2] = fmaf(e, wlo.z, acc[r][2]);
                acc[r][3] = fmaf(e, wlo.w, acc[r][3]);
                acc[r][4] = fmaf(e, whi.x, acc[r][4]);
                acc[r][5] = fmaf(e, whi.y, acc[r][5]);
                acc[r][6] = fmaf(e, whi.z, acc[r][6]);
                acc[r][7] = fmaf(e, whi.w, acc[r][7]);
            }
        }

        // ---- half 2: k = i0+4 .. i0+7 ----
#pragma unroll
        for (int r = 0; r < 8; ++r)
            a[r] = *reinterpret_cast<const float4*>(ap + r * D + i0 + 4);
#pragma unroll
        for (int u = 0; u < 4; ++u) {
            const float4 wlo = *reinterpret_cast<const float4*>(wp + (4 + u) * D);
            const float4 whi = *reinterpret_cast<const float4*>(wp + (4 + u) * D + 64);
#pragma unroll
            for (int r = 0; r < 8; ++r) {
                float e = (u == 0) ? a[r].x : (u == 1) ? a[r].y
                        : (u == 2) ? a[r].z : a[r].w;
                acc[r][0] = fmaf(e, wlo.x, acc[r][0]);
                acc[r][1] = fmaf(e, wlo.y, acc[r][1]);
                acc[r][2] = fmaf(e, wlo.z, acc[r][2]);
                acc[r][3] = fmaf(e, wlo.w, acc[r][3]);
                acc[r][4] = fmaf(e, whi.x, acc[r][4]);
                acc[r][5] = fmaf(e, whi.y, acc[r][5]);
                acc[r][6] = fmaf(e, whi.z, acc[r][6]);
                acc[r][7] = fmaf(e, whi.w, acc[r][7]);
            }
        }

        wp += 8 * D;
    }

#pragma unroll
    for (int r = 0; r < 8; ++r) {
        float* rowp = embW + (size_t)(row0 + r) * D;
        *reinterpret_cast<float4*>(rowp + jg * 4) =
            make_float4(acc[r][0], acc[r][1], acc[r][2], acc[r][3]);
        *reinterpret_cast<float4*>(rowp + 64 + jg * 4) =
            make_float4(acc[r][4], acc[r][5], acc[r][6], acc[r][7]);
    }
}

// ---------------------------------------------------------------------------
// Shared device helpers for the pair phase
// ---------------------------------------------------------------------------
__device__ __forceinline__ void block_softmaxes(const float* distance_att,
                                                const float* metapath_att,
                                                float* s_dis, float* s_mp,
                                                int tid)
{
    if (tid == 0) {
        float v[E];
        float mx = -1e30f;
        for (int i = 0; i < E; ++i) { v[i] = distance_att[i]; mx = fmaxf(mx, v[i]); }
        float sum = 0.f;
        for (int i = 0; i < E; ++i) { v[i] = expf(v[i] - mx); sum += v[i]; }
        for (int i = 0; i < E; ++i) s_dis[i] = v[i] / sum;

        float w[MPT];
        mx = -1e30f;
        for (int i = 0; i < MPT; ++i) { w[i] = metapath_att[i]; mx = fmaxf(mx, w[i]); }
        sum = 0.f;
        for (int i = 0; i < MPT; ++i) { w[i] = expf(w[i] - mx); sum += w[i]; }
        for (int i = 0; i < MPT; ++i) s_mp[i] = w[i] / sum;
    }
}

// Decode a task id into (src, dst, slot, weight).
__device__ __forceinline__ void decode_task(
    int task, int b, int s, int t, float tt, float dss, float dsdt,
    const float* __restrict__ delta,
    const float* __restrict__ s_dis, const float* __restrict__ s_mp,
    const int* __restrict__ mp_src, const int* __restrict__ mp_dst,
    const float* __restrict__ mp_time, const int* __restrict__ mp_dist,
    const int* __restrict__ mp_type,
    const int* __restrict__ neg_node,
    const int* __restrict__ neg_mp_src, const int* __restrict__ neg_mp_dst,
    const float* __restrict__ neg_mp_time, const int* __restrict__ neg_mp_dist,
    const int* __restrict__ neg_mp_type,
    int& srcn, int& dstn, int& slot, float& wgt)
{
    if (task == 0) {
        srcn = s; dstn = t; slot = 0; wgt = 1.f;
    } else if (task <= MXE) {
        int pe = task - 1;          // pe = m*E + e
        int m  = pe / E;
        int idx = b * MXE + pe;
        srcn = mp_src[idx];
        dstn = mp_dst[idx];
        slot = 0;
        float dec = expf(-dsdt * fabsf(tt - mp_time[idx]));
        wgt = s_dis[mp_dist[idx]] * dec * s_mp[mp_type[b * M + m]];
    } else if (task <= MXE + Q) {
        int q = task - 1 - MXE;
        srcn = s;                   // bilinear src is s (asymmetric!)
        dstn = neg_node[b * Q + q];
        slot = 1 + q;
        wgt  = 1.f;
    } else {
        int ne  = task - 1 - MXE - Q;   // ne = q*MXE + m*E + e
        int q   = ne / MXE;
        int rem = ne - q * MXE;
        int m   = rem / E;
        int idx = (b * Q + q) * MXE + rem;
        srcn = neg_mp_src[idx];
        dstn = neg_mp_dst[idx];
        slot = 1 + q;
        float dneg = delta[neg_node[b * Q + q]];
        float dec  = expf(-(dss * dneg) * fabsf(tt - neg_mp_time[idx]));
        wgt = s_dis[neg_mp_dist[idx]] * dec * s_mp[neg_mp_type[(b * Q + q) * M + m]];
    }
}

__device__ __forceinline__ void epilogue(const float* slots, float* out, int b)
{
    const float eps = 1e-6f;
    float p = slots[0];
    float loss = -logf(1.f / (1.f + expf(-p)) + eps);
#pragma unroll
    for (int q = 0; q < Q; ++q) {
        float v = slots[1 + q];
        loss -= logf(1.f / (1.f + expf(v)) + eps);   // log(sigmoid(-v)+eps)
    }
    out[b] = loss;
}

// ---------------------------------------------------------------------------
// Kernel 2: per-b weighted-dot accumulation + log-sigmoid epilogue.
// 1024 threads = 64 x 16-lane subgroups per b (unchanged; <=63us measured).
// ---------------------------------------------------------------------------
__global__ __launch_bounds__(1024)
void pair_kernel(const float* __restrict__ emb,
                 const float* __restrict__ embW,
                 const float* __restrict__ delta,
                 const float* __restrict__ distance_att,
                 const float* __restrict__ metapath_att,
                 const int*   __restrict__ s_node,
                 const int*   __restrict__ t_node,
                 const float* __restrict__ s_t_time,
                 const int*   __restrict__ mp_src,
                 const int*   __restrict__ mp_dst,
                 const float* __restrict__ mp_time,
                 const int*   __restrict__ mp_dist,
                 const int*   __restrict__ mp_type,
                 const int*   __restrict__ neg_node,
                 const int*   __restrict__ neg_mp_src,
                 const int*   __restrict__ neg_mp_dst,
                 const float* __restrict__ neg_mp_time,
                 const int*   __restrict__ neg_mp_dist,
                 const int*   __restrict__ neg_mp_type,
                 float* __restrict__ out)
{
    __shared__ float slots[1 + Q];
    __shared__ float s_dis[E];
    __shared__ float s_mp[MPT];

    const int b   = blockIdx.x;
    const int tid = threadIdx.x;

    if (tid < 1 + Q) slots[tid] = 0.f;
    block_softmaxes(distance_att, metapath_att, s_dis, s_mp, tid);
    __syncthreads();

    const int   s    = s_node[b];
    const int   t    = t_node[b];
    const float tt   = s_t_time[b];
    const float dss  = delta[s];
    const float dsdt = dss * delta[t];

    const int sg = tid >> 4;   // subgroup 0..63
    const int ln = tid & 15;   // lane in subgroup

    for (int task = sg; task < TASKS; task += 64) {
        int srcn, dstn, slot;
        float wgt;
        decode_task(task, b, s, t, tt, dss, dsdt, delta, s_dis, s_mp,
                    mp_src, mp_dst, mp_time, mp_dist, mp_type,
                    neg_node, neg_mp_src, neg_mp_dst, neg_mp_time,
                    neg_mp_dist, neg_mp_type, srcn, dstn, slot, wgt);

        // 128-dim dot: 16 lanes x 8 elements (2x float4 each side)
        const float4* pa = reinterpret_cast<const float4*>(embW + (size_t)srcn * D + ln * 8);
        const float4* pb = reinterpret_cast<const float4*>(emb  + (size_t)dstn * D + ln * 8);
        float4 a0 = pa[0], a1 = pa[1];
        float4 b0 = pb[0], b1 = pb[1];
        float d = a0.x * b0.x + a0.y * b0.y + a0.z * b0.z + a0.w * b0.w
                + a1.x * b1.x + a1.y * b1.y + a1.z * b1.z + a1.w * b1.w;
        d += __shfl_xor(d, 8);
        d += __shfl_xor(d, 4);
        d += __shfl_xor(d, 2);
        d += __shfl_xor(d, 1);
        if (ln == 0) atomicAdd(&slots[slot], d * wgt);
    }
    __syncthreads();

    if (tid == 0) epilogue(slots, out, b);
}

// ---------------------------------------------------------------------------
// Fallback (workspace too small): one wave per task; computes v = emb[src]@W
// on the fly. One block (512 threads = 8 waves) per b. (Not used when ws_size
// is sufficient — counters confirm the fast path runs.)
// ---------------------------------------------------------------------------
__global__ __launch_bounds__(512)
void pair_direct(const float* __restrict__ emb,
                 const float* __restrict__ W,
                 const float* __restrict__ delta,
                 const float* __restrict__ distance_att,
                 const float* __restrict__ metapath_att,
                 const int*   __restrict__ s_node,
                 const int*   __restrict__ t_node,
                 const float* __restrict__ s_t_time,
                 const int*   __restrict__ mp_src,
                 const int*   __restrict__ mp_dst,
                 const float* __restrict__ mp_time,
                 const int*   __restrict__ mp_dist,
                 const int*   __restrict__ mp_type,
                 const int*   __restrict__ neg_node,
                 const int*   __restrict__ neg_mp_src,
                 const int*   __restrict__ neg_mp_dst,
                 const float* __restrict__ neg_mp_time,
                 const int*   __restrict__ neg_mp_dist,
                 const int*   __restrict__ neg_mp_type,
                 float* __restrict__ out)
{
    __shared__ float slots[1 + Q];
    __shared__ float s_dis[E];
    __shared__ float s_mp[MPT];

    const int b   = blockIdx.x;
    const int tid = threadIdx.x;

    if (tid < 1 + Q) slots[tid] = 0.f;
    block_softmaxes(distance_att, metapath_att, s_dis, s_mp, tid);
    __syncthreads();

    const int   s    = s_node[b];
    const int   t    = t_node[b];
    const float tt   = s_t_time[b];
    const float dss  = delta[s];
    const float dsdt = dss * delta[t];

    const int wave = tid >> 6;   // 0..7
    const int ln   = tid & 63;   // lane in wave

    for (int task = wave; task < TASKS; task += 8) {
        int srcn, dstn, slot;
        float wgt;
        decode_task(task, b, s, t, tt, dss, dsdt, delta, s_dis, s_mp,
                    mp_src, mp_dst, mp_time, mp_dist, mp_type,
                    neg_node, neg_mp_src, neg_mp_dst, neg_mp_time,
                    neg_mp_dist, neg_mp_type, srcn, dstn, slot, wgt);

        // v[j] = sum_i emb[src][i] * W[i][j]; lane ln owns cols ln and ln+64
        const float* erow = emb + (size_t)srcn * D;
        float v0 = 0.f, v1 = 0.f;
#pragma unroll 1
        for (int i = 0; i < D; ++i) {
            float a = erow[i];                    // broadcast across wave
            v0 = fmaf(a, W[i * D + ln], v0);      // coalesced 64-lane read
            v1 = fmaf(a, W[i * D + ln + 64], v1);
        }
        const float* drow = emb + (size_t)dstn * D;
        float d = v0 * drow[ln] + v1 * drow[ln + 64];
        // full 64-lane reduce
        d += __shfl_xor(d, 32);
        d += __shfl_xor(d, 16);
        d += __shfl_xor(d, 8);
        d += __shfl_xor(d, 4);
        d += __shfl_xor(d, 2);
        d += __shfl_xor(d, 1);
        if (ln == 0) atomicAdd(&slots[slot], d * wgt);
    }
    __syncthreads();

    if (tid == 0) epilogue(slots, out, b);
}

// ---------------------------------------------------------------------------
extern "C" void kernel_launch(void* const* d_in, const int* in_sizes, int n_in,
                              void* d_out, int out_size, void* d_ws, size_t ws_size,
                              hipStream_t stream)
{
    const float* emb          = (const float*)d_in[0];
    const float* delta        = (const float*)d_in[1];
    const float* W            = (const float*)d_in[2];
    const float* distance_att = (const float*)d_in[3];
    const float* metapath_att = (const float*)d_in[4];
    const int*   s_node       = (const int*)d_in[5];
    const int*   t_node       = (const int*)d_in[6];
    const float* s_t_time     = (const float*)d_in[7];
    const int*   mp_src       = (const int*)d_in[8];
    const int*   mp_dst       = (const int*)d_in[9];
    const float* mp_time      = (const float*)d_in[10];
    const int*   mp_dist      = (const int*)d_in[11];
    const int*   mp_type      = (const int*)d_in[12];
    const int*   neg_node     = (const int*)d_in[13];
    const int*   neg_mp_src   = (const int*)d_in[14];
    const int*   neg_mp_dst   = (const int*)d_in[15];
    const float* neg_mp_time  = (const float*)d_in[16];
    const int*   neg_mp_dist  = (const int*)d_in[17];
    const int*   neg_mp_type  = (const int*)d_in[18];

    const int N = in_sizes[1];       // delta has N elements
    const int B = in_sizes[5];       // s_node has B elements

    const size_t need = (size_t)N * D * sizeof(float);   // 51.2 MB

    if (ws_size >= need) {
        // Fast path: precompute embW = emb @ W, then gather-dots.
        float* embW = (float*)d_ws;
        int blocks1 = (N + 127) / 128;
        embw_gemm<<<blocks1, 256, 0, stream>>>(emb, W, embW, N);
        pair_kernel<<<B, 1024, 0, stream>>>(emb, embW, delta,
                                            distance_att, metapath_att,
                                            s_node, t_node, s_t_time,
                                            mp_src, mp_dst, mp_time, mp_dist, mp_type,
                                            neg_node, neg_mp_src, neg_mp_dst,
                                            neg_mp_time, neg_mp_dist, neg_mp_type,
                                            (float*)d_out);
    } else {
        // Fallback: direct evaluation, no workspace needed.
        pair_direct<<<B, 512, 0, stream>>>(emb, W, delta,
                                           distance_att, metapath_att,
                                           s_node, t_node, s_t_time,
                                           mp_src, mp_dst, mp_time, mp_dist, mp_type,
                                           neg_node, neg_mp_src, neg_mp_dst,
                                           neg_mp_time, neg_mp_dist, neg_mp_type,
                                           (float*)d_out);
    }
}